// Round 1
// baseline (211.683 us; speedup 1.0000x reference)
//
#include <hip/hip_runtime.h>
#include <stdint.h>

#define C_INPUTS 41024
#define C_KEFF   40960   // last 64 cols of W are zero -> skip exactly
#define C_L1     256
#define C_BATCH  2048
#define C_BK     64
#define C_MTILE  64
#define C_KSPLIT 8
#define C_KCHUNK (C_KEFF / C_KSPLIT)     // 5120
#define C_NITER  (C_KCHUNK / C_BK)       // 80
#define C_MBLOCKS (4096 / C_MTILE)       // 64
#define C_WTILE_BYTES (C_L1 * C_BK * 2)  // 32768 bytes per k-tile of W (bf16, swizzled)
#define C_NKTILES (C_KEFF / C_BK)        // 640
#define WS_W_BYTES ((size_t)C_L1 * C_KEFF * 2)      // 20,971,520
#define LDS_BUF_BYTES 40960                          // A(8KB) + W(32KB)
#define LDS_TOTAL (2 * LDS_BUF_BYTES)                // 81,920

typedef __attribute__((ext_vector_type(8))) short  short8;
typedef __attribute__((ext_vector_type(4))) short  short4v;
typedef __attribute__((ext_vector_type(4))) float  f32x4;

typedef __attribute__((address_space(1))) const uint32_t g_as1_u32;
typedef __attribute__((address_space(3))) uint32_t      l_as3_u32;

__device__ __forceinline__ uint16_t bf16_rtne(float f) {
  uint32_t u = __builtin_bit_cast(uint32_t, f);
  u += 0x7fffu + ((u >> 16) & 1u);
  return (uint16_t)(u >> 16);
}

// ---------------------------------------------------------------------------
// Kernel 1: convert W [256, 41024] f32 -> bf16 workspace, K-tiled (BK=64),
// XOR-swizzled within each row (16B groups: g ^= row&7) so the GEMM's
// ds_read_b128 B-fragments are bank-conflict free while global_load_lds
// stays a linear copy (pre-swizzled source, rule #21).
// Layout: wsW[kt][row 0..255][64 bf16 = 8 groups of 8, swizzled]
// ---------------------------------------------------------------------------
__global__ __launch_bounds__(256) void k_convert_w(const float* __restrict__ W,
                                                   uint16_t* __restrict__ wsW) {
  const int kt = blockIdx.x;    // 0..639
  const int t  = threadIdx.x;
  const int g  = t & 7;         // 8-elem group within row
  const int r0 = t >> 3;        // 0..31
  const float* src = W + (size_t)kt * C_BK + (size_t)g * 8;
  uint16_t* dstT = wsW + (size_t)kt * (C_L1 * C_BK);
#pragma unroll
  for (int p = 0; p < 8; ++p) {
    const int row = p * 32 + r0;
    const float4* s = (const float4*)(src + (size_t)row * C_INPUTS);
    float4 x = s[0];
    float4 y = s[1];
    union { uint16_t h[8]; short8 v; } u;
    u.h[0] = bf16_rtne(x.x); u.h[1] = bf16_rtne(x.y);
    u.h[2] = bf16_rtne(x.z); u.h[3] = bf16_rtne(x.w);
    u.h[4] = bf16_rtne(y.x); u.h[5] = bf16_rtne(y.y);
    u.h[6] = bf16_rtne(y.z); u.h[7] = bf16_rtne(y.w);
    const int slot = g ^ (row & 7);
    *(short8*)(dstT + (size_t)row * C_BK + (slot << 3)) = u.v;
  }
}

// ---------------------------------------------------------------------------
// Kernel 2: main GEMM. Block = (mb, ks): 64 rows x 256 cols over k-chunk 5120.
// 256 threads = 4 waves, each wave owns a 64x64 N-quadrant (4x4 frags of
// 16x16x32 bf16 MFMA). A staged f32->bf16 via regs (T14 split), W staged via
// global_load_lds (16B). Double-buffered 80KB LDS -> 2 blocks/CU.
// Partials (f32) to workspace: P[ks][row 0..4095][col 0..255].
// ---------------------------------------------------------------------------
__global__ __launch_bounds__(256, 2) void k_gemm(const float* __restrict__ w_in,
                                                 const float* __restrict__ b_in,
                                                 const uint16_t* __restrict__ wsW,
                                                 float* __restrict__ wsP) {
  extern __shared__ char smem[];
  const int bid  = blockIdx.x;
  const int ks   = bid & 7;     // k-split: xcd-affine (bid%8) -> per-XCD W chunk fits L2
  const int mb   = bid >> 3;    // 0..63
  const int tid  = threadIdx.x;
  const int wave = tid >> 6;
  const int lane = tid & 63;

  const int k0 = ks * C_KCHUNK;
  const float* Abase = (mb < 32)
      ? (w_in + (size_t)mb * C_MTILE * C_INPUTS)
      : (b_in + (size_t)(mb - 32) * C_MTILE * C_INPUTS);

  // A staging: 4 threads per row; thread holds k = s*16 + ac*4 + (0..3), s=0..3
  const int ar = tid >> 2;   // row 0..63
  const int ac = tid & 3;
  const float* aptr = Abase + (size_t)ar * C_INPUTS + k0 + ac * 4;

  // W global source (pre-swizzled, layout == LDS layout byte-for-byte)
  const char* wg = (const char*)wsW + (size_t)(ks * C_NITER) * C_WTILE_BYTES + (size_t)tid * 16;

  // Precompute fragment LDS byte offsets (within buffer)
  const int lrow = lane & 15;
  const int lg   = lane >> 4;
  int aoff[4][2], boff[4][2];
#pragma unroll
  for (int mi = 0; mi < 4; ++mi)
#pragma unroll
    for (int kk = 0; kk < 2; ++kk) {
      const int r = mi * 16 + lrow;
      aoff[mi][kk] = r * 128 + (((kk * 4 + lg) ^ (r & 7)) << 4);
    }
#pragma unroll
  for (int ni = 0; ni < 4; ++ni)
#pragma unroll
    for (int kk = 0; kk < 2; ++kk) {
      const int r = wave * 64 + ni * 16 + lrow;
      boff[ni][kk] = 8192 + r * 128 + (((kk * 4 + lg) ^ (r & 7)) << 4);
    }

  // A LDS write offsets: for s: group g = s*2 + (ac>>1), sub-8B = (ac&1)*8
  int awoff[4];
#pragma unroll
  for (int s = 0; s < 4; ++s) {
    const int gg = s * 2 + (ac >> 1);
    awoff[s] = ar * 128 + (((gg) ^ (ar & 7)) << 4) + ((ac & 1) << 3);
  }

  f32x4 acc[4][4];
#pragma unroll
  for (int i = 0; i < 4; ++i)
#pragma unroll
    for (int j = 0; j < 4; ++j) acc[i][j] = (f32x4){0.f, 0.f, 0.f, 0.f};

  float4 av[4];

  // ---- prologue: stage tile 0 into buffer 0 ----
  {
    const float4* p = (const float4*)aptr;
#pragma unroll
    for (int s = 0; s < 4; ++s) av[s] = p[s * 4];
#pragma unroll
    for (int c = 0; c < 8; ++c) {
      __builtin_amdgcn_global_load_lds((g_as1_u32*)(wg + c * 4096),
                                       (l_as3_u32*)(smem + 8192 + wave * 1024 + c * 4096),
                                       16, 0, 0);
    }
    char* ab = smem;
#pragma unroll
    for (int s = 0; s < 4; ++s) {
      union { uint16_t h[4]; short4v v; } u;
      u.h[0] = bf16_rtne(av[s].x); u.h[1] = bf16_rtne(av[s].y);
      u.h[2] = bf16_rtne(av[s].z); u.h[3] = bf16_rtne(av[s].w);
      *(short4v*)(ab + awoff[s]) = u.v;
    }
  }
  __syncthreads();

  int cur = 0;
#pragma unroll 1
  for (int it = 0; it < C_NITER; ++it) {
    const int nxt = cur ^ 1;
    const bool pf = (it + 1 < C_NITER);
    if (pf) {
      // issue next A global loads (held in regs; waitcnt lands at the cvt below)
      const float4* p = (const float4*)(aptr + (size_t)(it + 1) * C_BK);
#pragma unroll
      for (int s = 0; s < 4; ++s) av[s] = p[s * 4];
      // issue next W tile direct-to-LDS
      const char* wsrc = wg + (size_t)(it + 1) * C_WTILE_BYTES;
      char* wdst = smem + nxt * LDS_BUF_BYTES + 8192 + wave * 1024;
#pragma unroll
      for (int c = 0; c < 8; ++c) {
        __builtin_amdgcn_global_load_lds((g_as1_u32*)(wsrc + c * 4096),
                                         (l_as3_u32*)(wdst + c * 4096),
                                         16, 0, 0);
      }
    }

    // ---- compute current buffer ----
    {
      const char* ab = smem + cur * LDS_BUF_BYTES;
#pragma unroll
      for (int kk = 0; kk < 2; ++kk) {
        short8 af[4], bf[4];
#pragma unroll
        for (int mi = 0; mi < 4; ++mi) af[mi] = *(const short8*)(ab + aoff[mi][kk]);
#pragma unroll
        for (int ni = 0; ni < 4; ++ni) bf[ni] = *(const short8*)(ab + boff[ni][kk]);
#pragma unroll
        for (int mi = 0; mi < 4; ++mi)
#pragma unroll
          for (int ni = 0; ni < 4; ++ni)
            acc[mi][ni] = __builtin_amdgcn_mfma_f32_16x16x32_bf16(af[mi], bf[ni], acc[mi][ni], 0, 0, 0);
      }
    }

    if (pf) {
      // convert + write next A tile (vmcnt wait auto-inserted here)
      char* ab = smem + nxt * LDS_BUF_BYTES;
#pragma unroll
      for (int s = 0; s < 4; ++s) {
        union { uint16_t h[4]; short4v v; } u;
        u.h[0] = bf16_rtne(av[s].x); u.h[1] = bf16_rtne(av[s].y);
        u.h[2] = bf16_rtne(av[s].z); u.h[3] = bf16_rtne(av[s].w);
        *(short4v*)(ab + awoff[s]) = u.v;
      }
    }
    __syncthreads();   // drains vmcnt/lgkmcnt: W lds-loads + A ds_writes visible
    cur = nxt;
  }

  // ---- store partials: C/D layout col=lane&15, row=(lane>>4)*4+reg ----
  float* P = wsP + ((size_t)ks * 4096 + (size_t)mb * C_MTILE) * 256;
#pragma unroll
  for (int mi = 0; mi < 4; ++mi)
#pragma unroll
    for (int ni = 0; ni < 4; ++ni)
#pragma unroll
      for (int j = 0; j < 4; ++j) {
        const int rr = mi * 16 + lg * 4 + j;
        const int cc = wave * 64 + ni * 16 + lrow;
        P[(size_t)rr * 256 + cc] = acc[mi][ni][j];
      }
}

// ---------------------------------------------------------------------------
// Kernel 3: reduce 8 k-split partials for w-dot and b-dot, apply bias,
// perspective mix and clamp. One block per output row r; thread = col c.
// out[r][c]     = clip(us*w + them*b)
// out[r][256+c] = clip(us*b + them*w)
// ---------------------------------------------------------------------------
__global__ __launch_bounds__(256) void k_reduce(const float* __restrict__ wsP,
                                                const float* __restrict__ us,
                                                const float* __restrict__ them,
                                                const float* __restrict__ bias,
                                                float* __restrict__ out) {
  const int r = blockIdx.x;    // 0..2047
  const int c = threadIdx.x;   // 0..255
  float wd = 0.f, bd = 0.f;
#pragma unroll
  for (int s = 0; s < C_KSPLIT; ++s) {
    wd += wsP[((size_t)s * 4096 + r) * 256 + c];
    bd += wsP[((size_t)s * 4096 + 2048 + r) * 256 + c];
  }
  const float bi = bias[c];
  const float w = wd + bi;
  const float b = bd + bi;
  const float u = us[r];
  const float t = them[r];
  float o1 = u * w + t * b;
  float o2 = u * b + t * w;
  o1 = fminf(fmaxf(o1, 0.f), 1.f);
  o2 = fminf(fmaxf(o2, 0.f), 1.f);
  out[(size_t)r * 512 + c]       = o1;
  out[(size_t)r * 512 + 256 + c] = o2;
}

extern "C" void kernel_launch(void* const* d_in, const int* in_sizes, int n_in,
                              void* d_out, int out_size, void* d_ws, size_t ws_size,
                              hipStream_t stream) {
  const float* us   = (const float*)d_in[0];
  const float* them = (const float*)d_in[1];
  const float* w_in = (const float*)d_in[2];
  const float* b_in = (const float*)d_in[3];
  const float* W    = (const float*)d_in[4];
  const float* bias = (const float*)d_in[5];
  float* out = (float*)d_out;

  uint16_t* wsW = (uint16_t*)d_ws;
  float*    wsP = (float*)((char*)d_ws + WS_W_BYTES);

  k_convert_w<<<C_NKTILES, 256, 0, stream>>>(W, wsW);
  k_gemm<<<C_MBLOCKS * C_KSPLIT, 256, LDS_TOTAL, stream>>>(w_in, b_in, wsW, wsP);
  k_reduce<<<C_BATCH, 256, 0, stream>>>(wsP, us, them, bias, out);
}